// Round 12
// baseline (191.920 us; speedup 1.0000x reference)
//
#include <hip/hip_runtime.h>

typedef __bf16 v8bf __attribute__((ext_vector_type(8)));
typedef float f32x4 __attribute__((ext_vector_type(4)));
typedef unsigned short u16x8 __attribute__((ext_vector_type(8)));

#define SLEN 256
#define BATCH 256
#define DIM 512
#define SCALE 0.044194173824159216f  // sqrt(1/512)

// fallback-path tile params (round-1 verified kernels)
#define TS 64
#define LDX 520
#define LDB 72
#define KC 64

#define MFMA(a, b, c) __builtin_amdgcn_mfma_f32_16x16x32_bf16((a), (b), (c), 0, 0, 0)

__device__ __forceinline__ unsigned int f2bf(float f) {
  union { float f; unsigned int u; } v; v.f = f;
  unsigned int r = v.u + 0x7FFFu + ((v.u >> 16) & 1u);  // RNE
  return r >> 16;
}
__device__ __forceinline__ float bf2f(unsigned short u) {
  union { unsigned int u; float f; } v; v.u = ((unsigned int)u) << 16;
  return v.f;
}
__device__ __forceinline__ v8bf ld8(const unsigned short* p) {
  u16x8 t = *reinterpret_cast<const u16x8*>(p);
  return __builtin_bit_cast(v8bf, t);
}
// async global->LDS, 16B per lane; lds base must be wave-uniform
__device__ __forceinline__ void gload16(const unsigned short* g, unsigned short* l) {
  __builtin_amdgcn_global_load_lds(
      (const __attribute__((address_space(1))) unsigned int*)g,
      (__attribute__((address_space(3))) unsigned int*)l, 16, 0, 0);
}

// ---------- zf: fast zero-fill (fallback path only) ----------
__global__ __launch_bounds__(256) void zf(float4* __restrict__ p, int n4) {
  const int i = blockIdx.x * 256 + threadIdx.x;
  if (i < n4) {
    const float4 z = {0.f, 0.f, 0.f, 0.f};
    p[i] = z;
  }
}

// ---------- prep_small: Mt (256 blk) + conv_wv (256) + wkr (2) ----------
__global__ __launch_bounds__(256) void prep_small(const float* __restrict__ Wq,
                                                  const float* __restrict__ Wk,
                                                  const float* __restrict__ Wv,
                                                  const float* __restrict__ rq,
                                                  unsigned short* __restrict__ Mt,
                                                  unsigned short* __restrict__ Wvb,
                                                  float* __restrict__ wkr) {
  __shared__ float As[32][33];
  __shared__ float Bs[32][33];
  const int blk = blockIdx.x;
  const int tid = threadIdx.x;

  if (blk < 256) {
    const int e0 = (blk & 15) * 32;
    const int d0 = (blk >> 4) * 32;
    const int tm = (tid & 15) * 2;
    const int tn = (tid >> 4) * 2;
    const int lf = tid >> 3;
    const int lc = (tid & 7) * 4;
    float a00 = 0.f, a01 = 0.f, a10 = 0.f, a11 = 0.f;
    for (int f0 = 0; f0 < DIM; f0 += 32) {
      __syncthreads();
      const float4 a = *reinterpret_cast<const float4*>(Wk + (size_t)(f0 + lf) * DIM + e0 + lc);
      const float4 b = *reinterpret_cast<const float4*>(Wq + (size_t)(f0 + lf) * DIM + d0 + lc);
      As[lf][lc] = a.x; As[lf][lc + 1] = a.y; As[lf][lc + 2] = a.z; As[lf][lc + 3] = a.w;
      Bs[lf][lc] = b.x; Bs[lf][lc + 1] = b.y; Bs[lf][lc + 2] = b.z; Bs[lf][lc + 3] = b.w;
      __syncthreads();
#pragma unroll
      for (int k = 0; k < 32; ++k) {
        const float x0 = As[k][tm], x1 = As[k][tm + 1];
        const float y0 = Bs[k][tn], y1 = Bs[k][tn + 1];
        a00 += x0 * y0; a01 += x0 * y1; a10 += x1 * y0; a11 += x1 * y1;
      }
    }
    Mt[(size_t)(e0 + tm) * DIM + d0 + tn] = (unsigned short)f2bf(a00);
    Mt[(size_t)(e0 + tm) * DIM + d0 + tn + 1] = (unsigned short)f2bf(a01);
    Mt[(size_t)(e0 + tm + 1) * DIM + d0 + tn] = (unsigned short)f2bf(a10);
    Mt[(size_t)(e0 + tm + 1) * DIM + d0 + tn + 1] = (unsigned short)f2bf(a11);
  } else if (blk < 512) {
    const int idx = ((blk - 256) * 256 + tid) * 4;
    const float4 v = *reinterpret_cast<const float4*>(Wv + idx);
    uint2 p;
    p.x = f2bf(v.x) | (f2bf(v.y) << 16);
    p.y = f2bf(v.z) | (f2bf(v.w) << 16);
    *reinterpret_cast<uint2*>(Wvb + idx) = p;
  } else {
    float* rqs = &As[0][0];
    rqs[tid] = rq[tid];
    rqs[tid + 256] = rq[tid + 256];
    __syncthreads();
    const int d = (blk - 512) * 256 + tid;
    float s = 0.f;
#pragma unroll 8
    for (int f = 0; f < DIM; ++f) s += Wk[(size_t)f * DIM + d] * rqs[f];
    wkr[d] = s;
  }
}

// ---------- gemm1_x: A from f32 X via depth-2 counted-vmcnt reg-staging pipeline.
// Writes own e-slice of converted X to Xsb (stores issued AFTER the end-of-iter
// counted wait so the vmcnt ledger stays exact). Raw s_barrier (no vmcnt(0)
// drain) keeps A-prefetch for tile t+2 in flight across 2 MFMA phases.
__global__ __launch_bounds__(512, 2) void gemm1_x(const float* __restrict__ X,
                                                  const unsigned short* __restrict__ Mt,
                                                  const float* __restrict__ wkr,
                                                  unsigned short* __restrict__ Xsb,
                                                  float* __restrict__ rdpart) {
  __shared__ unsigned short lds[32768];  // 64 KiB: 2 x (A 16KB + B 16KB)
  const int tid = threadIdx.x;
  const int lane = tid & 63, w = tid >> 6;
  const int wr = w >> 2, wc = w & 3;
  const int c = lane & 15, g = lane >> 4;
  const int grd = ((g ^ ((c >> 1) & 3))) * 8;

  const int work = (blockIdx.x & 7) * 64 + (blockIdx.x >> 3);  // 512 blocks, 8 XCDs
  const int rt = work >> 1, ct = work & 1;
  const int j0 = rt * 256, e0 = ct * 256;

  const int rA = tid >> 1;
  const int h = tid & 1;
  const int sw = (rA >> 1) & 3;
  const int q1 = (2 * h) ^ sw;
  const int q2 = (2 * h + 1) ^ sw;
  const float* xrowp = X + ((size_t)rA * BATCH + rt) * DIM;
  unsigned short* xsrow = Xsb + ((size_t)rA * BATCH + rt) * DIM;

  const int rB = tid >> 2;
  const int glB = (tid & 3) ^ ((rB >> 1) & 3);
  const unsigned short* sBp = Mt + (size_t)(e0 + rB) * DIM + glB * 8;

#define GB1(t) {                                                                \
    const int kc_ = (t) * 32;                                                   \
    unsigned short* lb_ = lds + ((t) & 1) * 16384 + 8192 + (w << 9);            \
    gload16(sBp + kc_, lb_);                                                    \
    gload16(sBp + kc_ + (size_t)128 * DIM, lb_ + 4096); }

#define LA2(t, A0, A1, A2, A3) {                                                \
    const int kc_ = (t) * 32;                                                   \
    A0 = *reinterpret_cast<const float4*>(xrowp + kc_ + q1 * 8);                \
    A1 = *reinterpret_cast<const float4*>(xrowp + kc_ + q1 * 8 + 4);            \
    A2 = *reinterpret_cast<const float4*>(xrowp + kc_ + q2 * 8);                \
    A3 = *reinterpret_cast<const float4*>(xrowp + kc_ + q2 * 8 + 4); }

#define PW1(t, A0, A1, A2, A3) {                                                \
    unsigned short* lb_ = lds + ((t) & 1) * 16384;                              \
    uint4 p1, p2;                                                               \
    p1.x = f2bf(A0.x) | (f2bf(A0.y) << 16);                                     \
    p1.y = f2bf(A0.z) | (f2bf(A0.w) << 16);                                     \
    p1.z = f2bf(A1.x) | (f2bf(A1.y) << 16);                                     \
    p1.w = f2bf(A1.z) | (f2bf(A1.w) << 16);                                     \
    p2.x = f2bf(A2.x) | (f2bf(A2.y) << 16);                                     \
    p2.y = f2bf(A2.z) | (f2bf(A2.w) << 16);                                     \
    p2.z = f2bf(A3.x) | (f2bf(A3.y) << 16);                                     \
    p2.w = f2bf(A3.z) | (f2bf(A3.w) << 16);                                     \
    *reinterpret_cast<uint4*>(lb_ + rA * 32 + (2 * h) * 8) = p1;                \
    *reinterpret_cast<uint4*>(lb_ + rA * 32 + (2 * h + 1) * 8) = p2; }

#define SX1(t, A0, A1, A2, A3) {                                                \
    const int kc_ = (t) * 32;                                                   \
    uint4 p1, p2;                                                               \
    p1.x = f2bf(A0.x) | (f2bf(A0.y) << 16);                                     \
    p1.y = f2bf(A0.z) | (f2bf(A0.w) << 16);                                     \
    p1.z = f2bf(A1.x) | (f2bf(A1.y) << 16);                                     \
    p1.w = f2bf(A1.z) | (f2bf(A1.w) << 16);                                     \
    p2.x = f2bf(A2.x) | (f2bf(A2.y) << 16);                                     \
    p2.y = f2bf(A2.z) | (f2bf(A2.w) << 16);                                     \
    p2.z = f2bf(A3.x) | (f2bf(A3.y) << 16);                                     \
    p2.w = f2bf(A3.z) | (f2bf(A3.w) << 16);                                     \
    *reinterpret_cast<uint4*>(xsrow + kc_ + q1 * 8) = p1;                       \
    *reinterpret_cast<uint4*>(xsrow + kc_ + q2 * 8) = p2; }

#define CMP1(t) {                                                               \
    const unsigned short* la = lds + ((t) & 1) * 16384;                         \
    const unsigned short* lb2 = la + 8192;                                      \
    v8bf a[8], bbf[4];                                                          \
    _Pragma("unroll")                                                           \
    for (int m = 0; m < 8; ++m)                                                 \
      a[m] = ld8(la + (wr * 128 + m * 16 + c) * 32 + grd);                      \
    _Pragma("unroll")                                                           \
    for (int n = 0; n < 4; ++n)                                                 \
      bbf[n] = ld8(lb2 + (wc * 64 + n * 16 + c) * 32 + grd);                    \
    __builtin_amdgcn_s_setprio(1);                                              \
    _Pragma("unroll")                                                           \
    for (int m = 0; m < 8; ++m)                                                 \
      _Pragma("unroll")                                                         \
      for (int n = 0; n < 4; ++n) acc[m][n] = MFMA(a[m], bbf[n], acc[m][n]);    \
    __builtin_amdgcn_s_setprio(0); }

// One pipeline sub-iteration. vmcnt ledger (FIFO, B issued before A):
//   entering iter t: [A(t+1)x4 (+stx2 if stores issued at iter t-1)]
//   issue B(t+1)x2 then A(t+2)x4
//   pre-WRITE wait retires exactly A(t+1): vmcnt( (t>>3)==ct ? 8 : 6 )  [t<=13]
//   end wait retires B(t+1) (+old st):     vmcnt(4)                     [t<=13]
//   t==14: pre = ct?4:2 ; end = 0.  Stores for tile t+1 issued after end wait.
#define SUBITER(T, L0, L1, L2, L3, W0, W1, W2, W3)                              \
  {                                                                             \
    const int t_ = (T);                                                         \
    if (t_ + 1 < 16) { GB1(t_ + 1); }                                           \
    __builtin_amdgcn_sched_barrier(0);                                          \
    if (t_ + 2 < 16) { LA2(t_ + 2, L0, L1, L2, L3); }                           \
    __builtin_amdgcn_sched_barrier(0);                                          \
    CMP1(t_);                                                                   \
    if (t_ + 1 < 16) {                                                          \
      if (t_ <= 13) {                                                           \
        if ((t_ >> 3) == ct) { asm volatile("s_waitcnt vmcnt(8)" ::: "memory"); }\
        else                 { asm volatile("s_waitcnt vmcnt(6)" ::: "memory"); }\
      } else {                                                                  \
        if (ct == 1) { asm volatile("s_waitcnt vmcnt(4)" ::: "memory"); }       \
        else         { asm volatile("s_waitcnt vmcnt(2)" ::: "memory"); }       \
      }                                                                         \
      __builtin_amdgcn_sched_barrier(0);                                        \
      PW1(t_ + 1, W0, W1, W2, W3);                                              \
      if (t_ <= 13) { asm volatile("s_waitcnt vmcnt(4)" ::: "memory"); }        \
      else          { asm volatile("s_waitcnt vmcnt(0)" ::: "memory"); }        \
      __builtin_amdgcn_sched_barrier(0);                                        \
      if (((t_ + 1) >> 3) == ct) { SX1(t_ + 1, W0, W1, W2, W3); }               \
      asm volatile("s_waitcnt lgkmcnt(0)" ::: "memory");                        \
      __builtin_amdgcn_sched_barrier(0);                                        \
      __builtin_amdgcn_s_barrier();                                             \
    }                                                                           \
  }

  f32x4 acc[8][4] = {};
  float4 ea0, ea1, ea2, ea3, oa0, oa1, oa2, oa3;

  // prologue: tile0 -> even set, tile1 -> odd set; queue after: [A1x4 (+st if ct0)]
  GB1(0);
  __builtin_amdgcn_sched_barrier(0);
  LA2(0, ea0, ea1, ea2, ea3);
  LA2(1, oa0, oa1, oa2, oa3);
  __builtin_amdgcn_sched_barrier(0);
  asm volatile("s_waitcnt vmcnt(4)" ::: "memory");  // retires B0x2 + A0x4
  __builtin_amdgcn_sched_barrier(0);
  PW1(0, ea0, ea1, ea2, ea3);
  if (ct == 0) { SX1(0, ea0, ea1, ea2, ea3); }
  asm volatile("s_waitcnt lgkmcnt(0)" ::: "memory");
  __builtin_amdgcn_sched_barrier(0);
  __builtin_amdgcn_s_barrier();

  for (int tt = 0; tt < 16; tt += 2) {
    SUBITER(tt,     ea0, ea1, ea2, ea3, oa0, oa1, oa2, oa3);
    SUBITER(tt + 1, oa0, oa1, oa2, oa3, ea0, ea1, ea2, ea3);
  }
  __syncthreads();  // full drain (incl. Xsb stores) before LDS reuse + readback

#undef GB1
#undef LA2
#undef PW1
#undef SX1
#undef CMP1
#undef SUBITER

  // epilogue: per-row dot over this block's e-slice (reads back own Xsb writes)
  float* red = (float*)lds;  // 4 wc-slices x 256 rows
  float wkrl[4];
#pragma unroll
  for (int n = 0; n < 4; ++n) wkrl[n] = wkr[e0 + wc * 64 + n * 16 + c];
#pragma unroll
  for (int m = 0; m < 8; ++m) {
#pragma unroll
    for (int i = 0; i < 4; ++i) {
      const int rl = wr * 128 + m * 16 + 4 * g + i;
      const unsigned short* xrow = Xsb + ((size_t)rl * BATCH + rt) * DIM + e0 + wc * 64 + c;
      float val = 0.f;
#pragma unroll
      for (int n = 0; n < 4; ++n)
        val += (acc[m][n][i] + wkrl[n]) * bf2f(xrow[n * 16]);
      val += __shfl_xor(val, 1); val += __shfl_xor(val, 2);
      val += __shfl_xor(val, 4); val += __shfl_xor(val, 8);
      if (c == 0) red[wc * 256 + rl] = val;
    }
  }
  __syncthreads();
  if (tid < 256) {
    const float s = red[tid] + red[256 + tid] + red[512 + tid] + red[768 + tid];
    rdpart[(size_t)ct * 65536 + j0 + tid] = s;
  }
}

// ============ verified round-9 deep-pipelined GEMM core for gemm2 ============
#define GEMM_PROLOGUE()                                                         \
  f32x4 acc[8][4] = {};                                                         \
  STG(0); STG(1); STG(2);

#define GEMM_MAIN_LOOP()                                                        \
  for (int t = 0; t < 16; ++t) {                                                \
    if (t <= 13) { asm volatile("s_waitcnt vmcnt(8)" ::: "memory"); }           \
    else if (t == 14) { asm volatile("s_waitcnt vmcnt(4)" ::: "memory"); }      \
    else { asm volatile("s_waitcnt vmcnt(0)" ::: "memory"); }                   \
    __builtin_amdgcn_s_barrier();                                               \
    __builtin_amdgcn_sched_barrier(0);                                          \
    if (t + 3 < 16) { STG(t + 3); }                                             \
    __builtin_amdgcn_sched_barrier(0);                                          \
    const unsigned short* la = ldsp + (t & 3) * 16384;                          \
    const unsigned short* lb2 = la + 8192;                                      \
    v8bf a[8], bbf[4];                                                          \
    _Pragma("unroll")                                                           \
    for (int m = 0; m < 8; ++m)                                                 \
      a[m] = ld8(la + (wr * 128 + m * 16 + c) * 32 + grd);                      \
    _Pragma("unroll")                                                           \
    for (int n = 0; n < 4; ++n)                                                 \
      bbf[n] = ld8(lb2 + (wc * 64 + n * 16 + c) * 32 + grd);                    \
    __builtin_amdgcn_s_setprio(1);                                              \
    _Pragma("unroll")                                                           \
    for (int m = 0; m < 8; ++m)                                                 \
      _Pragma("unroll")                                                         \
      for (int n = 0; n < 4; ++n) acc[m][n] = MFMA(a[m], bbf[n], acc[m][n]);    \
    __builtin_amdgcn_s_setprio(0);                                              \
  }

#define STG(tt) {                                                               \
    const int kc_ = (tt) * 32;                                                  \
    unsigned short* lb_ = lw + ((tt) & 3) * 16384;                              \
    gload16(sAp + kc_, lb_);                                                    \
    gload16(sAp + kc_ + sA2, lb_ + 4096);                                       \
    gload16(sBp + kc_, lb_ + 8192);                                             \
    gload16(sBp + kc_ + sB2, lb_ + 12288); }

// ---------- gemm2: rd/Rsum from rdpart; V = Xsb-rows @ Wvb^T; vs/vw in-block;
//            out = (rd_j/R - 1/s)*V + ((1-rd_j/R)/s)*vs + (1/(sR))*vw ----------
__global__ __launch_bounds__(512, 2) void gemm2_f(const unsigned short* __restrict__ Xsb,
                                                  const unsigned short* __restrict__ Wvb,
                                                  const float* __restrict__ rdpart,
                                                  float* __restrict__ out) {
  __shared__ unsigned short ldsp[65536];
  __shared__ float rdl[256];
  __shared__ float wsum[4];
  const int tid = threadIdx.x;
  const int lane = tid & 63, w = tid >> 6;
  const int wr = w >> 2, wc = w & 3;
  const int c = lane & 15, g = lane >> 4;
  const int grd = ((g ^ ((c >> 1) & 3))) * 8;

  const int work = (blockIdx.x & 7) * 64 + (blockIdx.x >> 3);
  const int rt = work >> 1, ct = work & 1;
  const int j0 = rt * 256, e0 = ct * 256;
  const int b = rt;

  if (tid < 256) {
    float v = (rdpart[(size_t)b * SLEN + tid] + rdpart[65536 + (size_t)b * SLEN + tid]) * SCALE;
    v = fminf(fmaxf(v, -5.0f), 7.0f);
    const float r = expf(v);
    rdl[tid] = r;
    float t = r;
    t += __shfl_xor(t, 1);  t += __shfl_xor(t, 2);  t += __shfl_xor(t, 4);
    t += __shfl_xor(t, 8);  t += __shfl_xor(t, 16); t += __shfl_xor(t, 32);
    if ((tid & 63) == 0) wsum[tid >> 6] = t;
  }
  __syncthreads();

  const int rA = tid >> 2;
  const int gl = (tid & 3) ^ ((rA >> 1) & 3);
  const unsigned short* sAp = Xsb + ((size_t)rA * BATCH + b) * DIM + gl * 8;
  const unsigned short* sBp = Wvb + (size_t)(e0 + rA) * DIM + gl * 8;
  const size_t sA2 = (size_t)128 * BATCH * DIM;
  const size_t sB2 = (size_t)128 * DIM;
  unsigned short* lw = ldsp + (w << 9);

  GEMM_PROLOGUE()
  GEMM_MAIN_LOOP()

  float vsp[4] = {0.f, 0.f, 0.f, 0.f}, vwp[4] = {0.f, 0.f, 0.f, 0.f};
#pragma unroll
  for (int m = 0; m < 8; ++m) {
#pragma unroll
    for (int i = 0; i < 4; ++i) {
      const int rl = wr * 128 + m * 16 + 4 * g + i;
      const float rr = rdl[rl];
#pragma unroll
      for (int n = 0; n < 4; ++n) {
        vsp[n] += acc[m][n][i];
        vwp[n] += rr * acc[m][n][i];
      }
    }
  }
#pragma unroll
  for (int n = 0; n < 4; ++n) {
    vsp[n] += __shfl_xor(vsp[n], 16); vsp[n] += __shfl_xor(vsp[n], 32);
    vwp[n] += __shfl_xor(vwp[n], 16); vwp[n] += __shfl_xor(vwp[n], 32);
  }
  __syncthreads();
  float* red = (float*)ldsp;
  if (g == 0) {
#pragma unroll
    for (int n = 0; n < 4; ++n) {
      red[(w * 4 + n) * 16 + c] = vsp[n];
      red[512 + (w * 4 + n) * 16 + c] = vwp[n];
    }
  }
  __syncthreads();
  const float Rb = wsum[0] + wsum[1] + wsum[2] + wsum[3];
  const float invR = 1.0f / Rb;
  const float gam = invR * 0.00390625f;
  const int wo = w ^ 4;
  float vsf[4], vwf[4];
#pragma unroll
  for (int n = 0; n < 4; ++n) {
    vsf[n] = red[(w * 4 + n) * 16 + c] + red[(wo * 4 + n) * 16 + c];
    vwf[n] = red[512 + (w * 4 + n) * 16 + c] + red[512 + (wo * 4 + n) * 16 + c];
  }
#pragma unroll
  for (int m = 0; m < 8; ++m) {
#pragma unroll
    for (int i = 0; i < 4; ++i) {
      const int rl = wr * 128 + m * 16 + 4 * g + i;
      const float tt = rdl[rl] * invR;
      const float al = tt - 0.00390625f;
      const float be = (1.0f - tt) * 0.00390625f;
      float* orow = out + (size_t)(j0 + rl) * DIM + e0 + wc * 64 + c;
#pragma unroll
      for (int n = 0; n < 4; ++n)
        orow[n * 16] = al * acc[m][n][i] + be * vsf[n] + gam * vwf[n];
    }
  }
}

// =================== round-1 fallback kernels (verified) ===================
__global__ __launch_bounds__(256) void prep_mt(const float* __restrict__ Wq,
                                               const float* __restrict__ Wk,
                                               unsigned short* __restrict__ Mt) {
  __shared__ float As[32][33];
  __shared__ float Bs[32][33];
  const int e0 = (blockIdx.x & 15) * 32;
  const int d0 = (blockIdx.x >> 4) * 32;
  const int tid = threadIdx.x;
  const int tm = (tid & 15) * 2;
  const int tn = (tid >> 4) * 2;
  const int lf = tid >> 3;
  const int lc = (tid & 7) * 4;
  float a00 = 0.f, a01 = 0.f, a10 = 0.f, a11 = 0.f;
  for (int f0 = 0; f0 < DIM; f0 += 32) {
    __syncthreads();
    const float4 a = *reinterpret_cast<const float4*>(Wk + (size_t)(f0 + lf) * DIM + e0 + lc);
    const float4 b = *reinterpret_cast<const float4*>(Wq + (size_t)(f0 + lf) * DIM + d0 + lc);
    As[lf][lc] = a.x; As[lf][lc + 1] = a.y; As[lf][lc + 2] = a.z; As[lf][lc + 3] = a.w;
    Bs[lf][lc] = b.x; Bs[lf][lc + 1] = b.y; Bs[lf][lc + 2] = b.z; Bs[lf][lc + 3] = b.w;
    __syncthreads();
#pragma unroll
    for (int k = 0; k < 32; ++k) {
      const float x0 = As[k][tm], x1 = As[k][tm + 1];
      const float y0 = Bs[k][tn], y1 = Bs[k][tn + 1];
      a00 += x0 * y0; a01 += x0 * y1; a10 += x1 * y0; a11 += x1 * y1;
    }
  }
  Mt[(size_t)(e0 + tm) * DIM + d0 + tn] = (unsigned short)f2bf(a00);
  Mt[(size_t)(e0 + tm) * DIM + d0 + tn + 1] = (unsigned short)f2bf(a01);
  Mt[(size_t)(e0 + tm + 1) * DIM + d0 + tn] = (unsigned short)f2bf(a10);
  Mt[(size_t)(e0 + tm + 1) * DIM + d0 + tn + 1] = (unsigned short)f2bf(a11);
}

__global__ __launch_bounds__(256) void conv_wv(const float* __restrict__ Wv,
                                               unsigned short* __restrict__ Wvb) {
  const int idx = (blockIdx.x * 256 + threadIdx.x) * 4;
  const float4 v = *reinterpret_cast<const float4*>(Wv + idx);
  uint2 p;
  p.x = f2bf(v.x) | (f2bf(v.y) << 16);
  p.y = f2bf(v.z) | (f2bf(v.w) << 16);
  *reinterpret_cast<uint2*>(Wvb + idx) = p;
}

__global__ __launch_bounds__(256) void wkr_k2(const float* __restrict__ Wk,
                                              const float* __restrict__ rq,
                                              float* __restrict__ wkr) {
  __shared__ float rqs[DIM];
  const int tid = threadIdx.x;
  rqs[tid] = rq[tid];
  rqs[tid + 256] = rq[tid + 256];
  __syncthreads();
  const int d = blockIdx.x * 256 + tid;
  float s = 0.f;
#pragma unroll 8
  for (int f = 0; f < DIM; ++f) s += Wk[(size_t)f * DIM + d] * rqs[f];
  wkr[d] = s;
}

__global__ __launch_bounds__(256, 2) void pass1_fb(
    const float* __restrict__ X, const unsigned short* __restrict__ Mt,
    const float* __restrict__ wkr, float* __restrict__ rd_out,
    float* __restrict__ Rsum, float* __restrict__ xsum, float* __restrict__ xw) {
  __shared__ __align__(16) unsigned short Xs[TS * LDX];
  __shared__ __align__(16) unsigned short Bsh[64 * LDB];
  __shared__ float wkrs[DIM];
  __shared__ float dacc[TS];
  __shared__ float rds[TS];
  const int tid = threadIdx.x;
  const int b = blockIdx.x & 255;
  const int s0 = (blockIdx.x >> 8) * TS;
  const int lane = tid & 63;
  const int wave = tid >> 6;
  const int wr = wave >> 1, wc = wave & 1;
  const int g = lane >> 4, c = lane & 15;
#pragma unroll 4
  for (int r = 0; r < TS; ++r) {
    const float2 v = *reinterpret_cast<const float2*>(
        X + ((size_t)(s0 + r) * BATCH + b) * DIM + tid * 2);
    Xs[r * LDX + tid * 2] = (unsigned short)f2bf(v.x);
    Xs[r * LDX + tid * 2 + 1] = (unsigned short)f2bf(v.y);
  }
  wkrs[tid] = wkr[tid];
  wkrs[tid + 256] = wkr[tid + 256];
  if (tid < TS) dacc[tid] = 0.f;
  float dp0[4] = {0.f, 0.f, 0.f, 0.f};
  float dp1[4] = {0.f, 0.f, 0.f, 0.f};
  for (int et = 0; et < 8; ++et) {
    const int e0 = et * 64;
    f32x4 acc00 = {0.f,0.f,0.f,0.f}, acc01 = {0.f,0.f,0.f,0.f};
    f32x4 acc10 = {0.f,0.f,0.f,0.f}, acc11 = {0.f,0.f,0.f,0.f};
    for (int kc0 = 0; kc0 < DIM; kc0 += KC) {
      __syncthreads();
      {
        const int e = tid >> 2;
        const int kq = (tid & 3) * 16;
        const uint4* src = reinterpret_cast<const uint4*>(Mt + (size_t)(e0 + e) * DIM + kc0 + kq);
        const uint4 w0 = src[0];
        const uint4 w1 = src[1];
        *reinterpret_cast<uint4*>(&Bsh[e * LDB + kq]) = w0;
        *reinterpret_cast<uint4*>(&Bsh[e * LDB + kq + 8]) = w1;
      }
      __syncthreads();
#pragma unroll
      for (int ks = 0; ks < KC; ks += 32) {
        const int ka = kc0 + ks + 8 * g;
        const int kb = ks + 8 * g;
        const v8bf fa0 = ld8(&Xs[(32 * wr + c) * LDX + ka]);
        const v8bf fa1 = ld8(&Xs[(32 * wr + 16 + c) * LDX + ka]);
        const v8bf fb0 = ld8(&Bsh[(32 * wc + c) * LDB + kb]);
        const v8bf fb1 = ld8(&Bsh[(32 * wc + 16 + c) * LDB + kb]);
        acc00 = MFMA(fa0, fb0, acc00);
        acc01 = MFMA(fa0, fb1, acc01);
        acc10 = MFMA(fa1, fb0, acc10);
        acc11 = MFMA(fa1, fb1, acc11);
      }
    }
#pragma unroll
    for (int i = 0; i < 4; ++i) {
      const int r0 = 32 * wr + 4 * g + i;
      const int ec0 = e0 + 32 * wc + c;
      const float w0 = wkrs[ec0], w1 = wkrs[ec0 + 16];
      dp0[i] += (acc00[i] + w0) * bf2f(Xs[r0 * LDX + ec0]) +
                (acc01[i] + w1) * bf2f(Xs[r0 * LDX + ec0 + 16]);
      dp1[i] += (acc10[i] + w0) * bf2f(Xs[(r0 + 16) * LDX + ec0]) +
                (acc11[i] + w1) * bf2f(Xs[(r0 + 16) * LDX + ec0 + 16]);
    }
  }
#pragma unroll
  for (int i = 0; i < 4; ++i) {
    float v0 = dp0[i], v1 = dp1[i];
    v0 += __shfl_xor(v0, 1); v0 += __shfl_xor(v0, 2);
    v0 += __shfl_xor(v0, 4); v0 += __shfl_xor(v0, 8);
    v1 += __shfl_xor(v1, 1); v1 += __shfl_xor(v1, 2);
    v1 += __shfl_xor(v1, 4); v1 += __shfl_xor(v1, 8);
    if (c == 0) {
      atomicAdd(&dacc[32 * wr + 4 * g + i], v0);
      atomicAdd(&dacc[32 * wr + 16 + 4 * g + i], v1);
    }
  }
  __syncthreads();
  if (tid < TS) {
    float sc = dacc[tid] * SCALE;
    sc = fminf(fmaxf(sc, -5.0f), 7.0f);
    const float r = expf(sc);
    rds[tid] = r;
    rd_out[(size_t)b * SLEN + s0 + tid] = r;
    float t = r;
    t += __shfl_xor(t, 1); t += __shfl_xor(t, 2); t += __shfl_xor(t, 4);
    t += __shfl_xor(t, 8); t += __shfl_xor(t, 16); t += __shfl_xor(t, 32);
    if (tid == 0) atomicAdd(&Rsum[b], t);
  }
  __syncthreads();
#pragma unroll
  for (int dd = 0; dd < 2; ++dd) {
    const int d = tid + dd * 256;
    float s1 = 0.f, s2 = 0.f;
    for (int r = 0; r < TS; ++r) {
      const float xv = bf2f(Xs[r * LDX + d]);
      s1 += xv;
      s2 += rds[r] * xv;
    }
    atomicAdd(&xsum[(size_t)b * DIM + d], s1);
    atomicAdd(&xw[(size_t)b * DIM + d], s2);
  }
}

__global__ __launch_bounds__(256, 2) void pass2_fb(
    const float* __restrict__ X, const unsigned short* __restrict__ Wvb,
    const float* __restrict__ rd, const float* __restrict__ Rsum,
    const float* __restrict__ xsum, const float* __restrict__ xw,
    float* __restrict__ out) {
  __shared__ __align__(16) unsigned short Zs[TS * LDX];
  __shared__ __align__(16) unsigned short Bsh[64 * LDB];
  __shared__ float xss[DIM];
  __shared__ float xws[DIM];
  __shared__ float rds[TS];
  const int tid = threadIdx.x;
  const int b = blockIdx.x & 255;
  const int s0 = (blockIdx.x >> 8) * TS;
  const int lane = tid & 63;
  const int wave = tid >> 6;
  const int wr = wave >> 1, wc = wave & 1;
  const int g = lane >> 4, c = lane & 15;
  xss[tid] = xsum[(size_t)b * DIM + tid];
  xss[tid + 256] = xsum[(size_t)b * DIM + tid + 256];
  xws[tid] = xw[(size_t)b * DIM + tid];
  xws[tid + 256] = xw[(size_t)b * DIM + tid + 256];
  if (tid < TS) rds[tid] = rd[(size_t)b * SLEN + s0 + tid];
  const float Rb = Rsum[b];
  const float invR = 1.0f / Rb;
  const float gam = invR * (1.0f / 256.0f);
  __syncthreads();
#pragma unroll 4
  for (int r = 0; r < TS; ++r) {
    const float rv = rds[r];
    const float al = rv * invR - (1.0f / 256.0f);
    const float be = (1.0f - rv * invR) * (1.0f / 256.0f);
    const float2 v = *reinterpret_cast<const float2*>(
        X + ((size_t)(s0 + r) * BATCH + b) * DIM + tid * 2);
    const int d0 = tid * 2;
    Zs[r * LDX + d0] = (unsigned short)f2bf(al * v.x + be * xss[d0] + gam * xws[d0]);
    Zs[r * LDX + d0 + 1] = (unsigned short)f2bf(al * v.y + be * xss[d0 + 1] + gam * xws[d0 + 1]);
  }
  const size_t outbase = ((size_t)b * SLEN + s0) * DIM;
  for (int et = 0; et < 8; ++et) {
    const int e0 = et * 64;
    f32x4 acc00 = {0.f,0.f,0.f,0.f}, acc01 = {0.f,0.f,0.f,0.f};
    f32x4 acc10 = {0.f,0.f,0.f,0.f}, acc11 = {0.f,0.f,0.f,0.f};
    for (int kc0 = 0; kc0 < DIM; kc0 += KC) {
      __syncthreads();
      {
        const int e = tid >> 2;
        const int kq = (tid & 3) * 16;
        const uint4* src = reinterpret_cast<const uint4*>(Wvb + (size_t)(e0 + e) * DIM + kc0 + kq);
        const uint4 w0 = src[0];
        const uint4 w1 = src[1];
        *reinterpret_cast<uint4*>(&Bsh[e * LDB + kq]) = w0;
        *reinterpret_cast<uint4*>(&Bsh[e * LDB + kq + 8]) = w1;
      }
      __syncthreads();
#pragma unroll
      for (int ks = 0; ks < KC; ks += 32) {
        const int ka = kc0 + ks + 8 * g;
        const int kb = ks + 8 * g;
        const v8bf fa0 = ld8(&Zs[(32 * wr + c) * LDX + ka]);
        const v8bf fa1 = ld8(&Zs[(32 * wr + 16 + c) * LDX + ka]);
        const v8bf fb0 = ld8(&Bsh[(32 * wc + c) * LDB + kb]);
        const v8bf fb1 = ld8(&Bsh[(32 * wc + 16 + c) * LDB + kb]);
        acc00 = MFMA(fa0, fb0, acc00);
        acc01 = MFMA(fa0, fb1, acc01);
        acc10 = MFMA(fa1, fb0, acc10);
        acc11 = MFMA(fa1, fb1, acc11);
      }
    }
#pragma unroll
    for (int i = 0; i < 4; ++i) {
      const int r0 = 32 * wr + 4 * g + i;
      const int c0 = e0 + 32 * wc + c;
      out[outbase + (size_t)r0 * DIM + c0] = acc00[i];
      out[outbase + (size_t)r0 * DIM + c0 + 16] = acc01[i];
      out[outbase + (size_t)(r0 + 16) * DIM + c0] = acc10[i];
      out[outbase + (size_t)(r0 + 16) * DIM + c0 + 16] = acc11[i];
    }
  }
}

extern "C" void kernel_launch(void* const* d_in, const int* in_sizes, int n_in,
                              void* d_out, int out_size, void* d_ws, size_t ws_size,
                              hipStream_t stream) {
  (void)in_sizes; (void)n_in; (void)out_size;
  const float* X = (const float*)d_in[0];
  const float* Wq = (const float*)d_in[1];
  const float* Wk = (const float*)d_in[2];
  const float* Wv = (const float*)d_in[3];
  const float* rq = (const float*)d_in[4];
  float* out = (float*)d_out;
  char* ws = (char*)d_ws;

  unsigned short* Mt = (unsigned short*)(ws + 0);        // 512 KB
  unsigned short* Wvb = (unsigned short*)(ws + 524288);  // 512 KB

  const size_t NEED = 69206016;  // 2 MB headers + 64 MB Xsb
  if (ws_size >= NEED) {
    float* wkr = (float*)(ws + 1048576);            // 2 KB  (plain stores)
    float* rdpart = (float*)(ws + 1052672);         // 512 KB [2][65536] (plain stores)
    unsigned short* Xsb = (unsigned short*)(ws + 2097152);  // 64 MB, s-major

    prep_small<<<dim3(514), dim3(256), 0, stream>>>(Wq, Wk, Wv, rq, Mt, Wvb, wkr);
    gemm1_x<<<dim3(512), dim3(512), 0, stream>>>(X, Mt, wkr, Xsb, rdpart);
    gemm2_f<<<dim3(512), dim3(512), 0, stream>>>(Xsb, Wvb, rdpart, out);
  } else {
    // round-1 verified fallback (needs ~2.4 MB)
    float* rd = (float*)(ws + 1048576);
    float* wkr = (float*)(ws + 1310720);
    float* Rsum = (float*)(ws + 1312768);
    float* xsum = (float*)(ws + 1313792);
    float* xw = (float*)(ws + 1838080);
    zf<<<dim3(257), dim3(256), 0, stream>>>((float4*)(ws + 1310720), 65728);
    prep_mt<<<dim3(256), dim3(256), 0, stream>>>(Wq, Wk, Mt);
    conv_wv<<<dim3(256), dim3(256), 0, stream>>>(Wv, Wvb);
    wkr_k2<<<dim3(2), dim3(256), 0, stream>>>(Wk, rq, wkr);
    pass1_fb<<<dim3(1024), dim3(256), 0, stream>>>(X, Mt, wkr, rd, Rsum, xsum, xw);
    pass2_fb<<<dim3(1024), dim3(256), 0, stream>>>(X, Wvb, rd, Rsum, xsum, xw, out);
  }
}

// Round 13
// 180.641 us; speedup vs baseline: 1.0624x; 1.0624x over previous
//
#include <hip/hip_runtime.h>

typedef __bf16 v8bf __attribute__((ext_vector_type(8)));
typedef float f32x4 __attribute__((ext_vector_type(4)));
typedef unsigned short u16x8 __attribute__((ext_vector_type(8)));

#define SLEN 256
#define BATCH 256
#define DIM 512
#define SCALE 0.044194173824159216f  // sqrt(1/512)

// fallback-path tile params (round-1 verified kernels)
#define TS 64
#define LDX 520
#define LDB 72
#define KC 64

#define MFMA(a, b, c) __builtin_amdgcn_mfma_f32_16x16x32_bf16((a), (b), (c), 0, 0, 0)

__device__ __forceinline__ unsigned int f2bf(float f) {
  union { float f; unsigned int u; } v; v.f = f;
  unsigned int r = v.u + 0x7FFFu + ((v.u >> 16) & 1u);  // RNE
  return r >> 16;
}
__device__ __forceinline__ float bf2f(unsigned short u) {
  union { unsigned int u; float f; } v; v.u = ((unsigned int)u) << 16;
  return v.f;
}
__device__ __forceinline__ v8bf ld8(const unsigned short* p) {
  u16x8 t = *reinterpret_cast<const u16x8*>(p);
  return __builtin_bit_cast(v8bf, t);
}
// async global->LDS, 16B per lane; lds base must be wave-uniform
__device__ __forceinline__ void gload16(const unsigned short* g, unsigned short* l) {
  __builtin_amdgcn_global_load_lds(
      (const __attribute__((address_space(1))) unsigned int*)g,
      (__attribute__((address_space(3))) unsigned int*)l, 16, 0, 0);
}

// ---------- zf: fast zero-fill (fallback path only) ----------
__global__ __launch_bounds__(256) void zf(float4* __restrict__ p, int n4) {
  const int i = blockIdx.x * 256 + threadIdx.x;
  if (i < n4) {
    const float4 z = {0.f, 0.f, 0.f, 0.f};
    p[i] = z;
  }
}

// ---------- prep_all: small roles first (dispatch order), bulk x2b last ----------
// blocks [0,256)   : prep_mt  (long-latency small grid -> starts at t=0)
// blocks [256,512) : conv_wv
// blocks [512,514) : wkr
// blocks [514,2562): x2b, 2048 blocks x 32 rows, pipelined loads + 16B stores.
// X-ingest is wall-capped at ~1.8 TB/s (rounds 2..9 falsified every pattern
// theory: scalar/batched/pipelined/LDS-tiled/sequential all ~equal).
__global__ __launch_bounds__(256) void prep_all(const float* __restrict__ X,
                                                const float* __restrict__ Wq,
                                                const float* __restrict__ Wk,
                                                const float* __restrict__ Wv,
                                                const float* __restrict__ rq,
                                                unsigned short* __restrict__ Xb,
                                                unsigned short* __restrict__ Mt,
                                                unsigned short* __restrict__ Wvb,
                                                float* __restrict__ wkr) {
  __shared__ float As[32][33];
  __shared__ float Bs[32][33];
  const int blk = blockIdx.x;
  const int tid = threadIdx.x;

  if (blk >= 514) {
    // ---- x2b role: X[s,b,d] f32 -> Xb[b,s,d] bf16, 32 rows per block ----
    const int id = blk - 514;
    const int b = id & 255;
    const int sc = id >> 8;        // 0..7
    const int s0 = sc * 32;
    const int l = tid & 63;
    const int rg = tid >> 6;       // 0..3
    const int d0 = l * 8;          // 8 floats per lane -> full 512-col row per wave
    const size_t rstride = (size_t)4 * BATCH * DIM;  // s advances by 4 per k
    const float* xp = X + ((size_t)(s0 + rg) * BATCH + b) * DIM + d0;
    unsigned short* op = Xb + ((size_t)b * SLEN + s0 + rg) * DIM + d0;
    float4 ca = *reinterpret_cast<const float4*>(xp);
    float4 cb = *reinterpret_cast<const float4*>(xp + 4);
#pragma unroll
    for (int k = 0; k < 8; ++k) {
      float4 na, nb;
      if (k < 7) {
        const float* nx = xp + (size_t)(k + 1) * rstride;
        na = *reinterpret_cast<const float4*>(nx);
        nb = *reinterpret_cast<const float4*>(nx + 4);
      }
      uint4 pq;
      pq.x = f2bf(ca.x) | (f2bf(ca.y) << 16);
      pq.y = f2bf(ca.z) | (f2bf(ca.w) << 16);
      pq.z = f2bf(cb.x) | (f2bf(cb.y) << 16);
      pq.w = f2bf(cb.z) | (f2bf(cb.w) << 16);
      *reinterpret_cast<uint4*>(op + (size_t)k * 4 * DIM) = pq;
      ca = na; cb = nb;
    }
  } else if (blk < 256) {
    // ---- prep_mt role: Mt[e][d] = sum_f Wk[f,e]*Wq[f,d] ----
    const int e0 = (blk & 15) * 32;
    const int d0 = (blk >> 4) * 32;
    const int tm = (tid & 15) * 2;
    const int tn = (tid >> 4) * 2;
    const int lf = tid >> 3;
    const int lc = (tid & 7) * 4;
    float a00 = 0.f, a01 = 0.f, a10 = 0.f, a11 = 0.f;
    for (int f0 = 0; f0 < DIM; f0 += 32) {
      __syncthreads();
      const float4 a = *reinterpret_cast<const float4*>(Wk + (size_t)(f0 + lf) * DIM + e0 + lc);
      const float4 b = *reinterpret_cast<const float4*>(Wq + (size_t)(f0 + lf) * DIM + d0 + lc);
      As[lf][lc] = a.x; As[lf][lc + 1] = a.y; As[lf][lc + 2] = a.z; As[lf][lc + 3] = a.w;
      Bs[lf][lc] = b.x; Bs[lf][lc + 1] = b.y; Bs[lf][lc + 2] = b.z; Bs[lf][lc + 3] = b.w;
      __syncthreads();
#pragma unroll
      for (int k = 0; k < 32; ++k) {
        const float x0 = As[k][tm], x1 = As[k][tm + 1];
        const float y0 = Bs[k][tn], y1 = Bs[k][tn + 1];
        a00 += x0 * y0; a01 += x0 * y1; a10 += x1 * y0; a11 += x1 * y1;
      }
    }
    Mt[(size_t)(e0 + tm) * DIM + d0 + tn] = (unsigned short)f2bf(a00);
    Mt[(size_t)(e0 + tm) * DIM + d0 + tn + 1] = (unsigned short)f2bf(a01);
    Mt[(size_t)(e0 + tm + 1) * DIM + d0 + tn] = (unsigned short)f2bf(a10);
    Mt[(size_t)(e0 + tm + 1) * DIM + d0 + tn + 1] = (unsigned short)f2bf(a11);
  } else if (blk < 512) {
    // ---- conv_wv role ----
    const int idx = ((blk - 256) * 256 + tid) * 4;
    const float4 v = *reinterpret_cast<const float4*>(Wv + idx);
    uint2 p;
    p.x = f2bf(v.x) | (f2bf(v.y) << 16);
    p.y = f2bf(v.z) | (f2bf(v.w) << 16);
    *reinterpret_cast<uint2*>(Wvb + idx) = p;
  } else {
    // ---- wkr role (2 blocks): wkr[d] = sum_f Wk[f,d]*rq[f], plain store ----
    float* rqs = &As[0][0];  // 512 floats fits in As
    rqs[tid] = rq[tid];
    rqs[tid + 256] = rq[tid + 256];
    __syncthreads();
    const int d = (blk - 512) * 256 + tid;
    float s = 0.f;
#pragma unroll 8
    for (int f = 0; f < DIM; ++f) s += Wk[(size_t)f * DIM + d] * rqs[f];
    wkr[d] = s;
  }
}

// ============ deep-pipelined 256x256 GEMM core (BK=32, 4 LDS buffers) ============
// Verified rounds 5-9. Swizzle: 16B granule gI at row r holds global granule
// gI ^ ((r>>1)&3); applied on pre-swizzled global source AND on ds_read.
// Counted vmcnt(8) = 2 tiles outstanding; prefetch distance 3 tiles.

#define GEMM_PROLOGUE()                                                         \
  f32x4 acc[8][4] = {};                                                         \
  STG(0); STG(1); STG(2);

#define GEMM_MAIN_LOOP()                                                        \
  for (int t = 0; t < 16; ++t) {                                                \
    if (t <= 13) { asm volatile("s_waitcnt vmcnt(8)" ::: "memory"); }           \
    else if (t == 14) { asm volatile("s_waitcnt vmcnt(4)" ::: "memory"); }      \
    else { asm volatile("s_waitcnt vmcnt(0)" ::: "memory"); }                   \
    __builtin_amdgcn_s_barrier();                                               \
    __builtin_amdgcn_sched_barrier(0);                                          \
    if (t + 3 < 16) { STG(t + 3); }                                             \
    __builtin_amdgcn_sched_barrier(0);                                          \
    const unsigned short* la = lds + (t & 3) * 16384;                           \
    const unsigned short* lb2 = la + 8192;                                      \
    v8bf a[8], bbf[4];                                                          \
    _Pragma("unroll")                                                           \
    for (int m = 0; m < 8; ++m)                                                 \
      a[m] = ld8(la + (wr * 128 + m * 16 + c) * 32 + grd);                      \
    _Pragma("unroll")                                                           \
    for (int n = 0; n < 4; ++n)                                                 \
      bbf[n] = ld8(lb2 + (wc * 64 + n * 16 + c) * 32 + grd);                    \
    __builtin_amdgcn_s_setprio(1);                                              \
    _Pragma("unroll")                                                           \
    for (int m = 0; m < 8; ++m)                                                 \
      _Pragma("unroll")                                                         \
      for (int n = 0; n < 4; ++n) acc[m][n] = MFMA(a[m], bbf[n], acc[m][n]);    \
    __builtin_amdgcn_s_setprio(0);                                              \
  }

#define STG(tt) {                                                               \
    const int kc_ = (tt) * 32;                                                  \
    unsigned short* lb_ = lw + ((tt) & 3) * 16384;                              \
    gload16(sAp + kc_, lb_);                                                    \
    gload16(sAp + kc_ + 128 * DIM, lb_ + 4096);                                 \
    gload16(sBp + kc_, lb_ + 8192);                                             \
    gload16(sBp + kc_ + 128 * DIM, lb_ + 12288); }

// ---------- gemm1: u = Xb @ Mt^T; rdpart[ct][j] = sum_e-slice (u+wkr)*x (no atomics) ----------
__global__ __launch_bounds__(512, 2) void gemm1_dp(const unsigned short* __restrict__ Xb,
                                                   const unsigned short* __restrict__ Mt,
                                                   const float* __restrict__ wkr,
                                                   float* __restrict__ rdpart) {
  __shared__ unsigned short lds[65536];  // 128 KiB
  const int tid = threadIdx.x;
  const int lane = tid & 63, w = tid >> 6;
  const int wr = w >> 2, wc = w & 3;
  const int c = lane & 15, g = lane >> 4;
  const int grd = ((g ^ ((c >> 1) & 3))) * 8;

  const int work = (blockIdx.x & 7) * 64 + (blockIdx.x >> 3);  // 512 blocks, 8 XCDs
  const int rt = work >> 1, ct = work & 1;
  const int j0 = rt * 256, e0 = ct * 256;

  const int rA = tid >> 2;
  const int gl = (tid & 3) ^ ((rA >> 1) & 3);
  const unsigned short* sAp = Xb + (size_t)(j0 + rA) * DIM + gl * 8;
  const unsigned short* sBp = Mt + (size_t)(e0 + rA) * DIM + gl * 8;
  unsigned short* lw = lds + (w << 9);

  GEMM_PROLOGUE()
  GEMM_MAIN_LOOP()

  // epilogue: per-row dot with x over this block's e-slice, LDS cross-wave combine
  __syncthreads();
  float* red = (float*)lds;  // 4 wc-slices x 256 rows
  float wkrl[4];
#pragma unroll
  for (int n = 0; n < 4; ++n) wkrl[n] = wkr[e0 + wc * 64 + n * 16 + c];
#pragma unroll
  for (int m = 0; m < 8; ++m) {
#pragma unroll
    for (int i = 0; i < 4; ++i) {
      const int rl = wr * 128 + m * 16 + 4 * g + i;
      const unsigned short* xrow = Xb + (size_t)(j0 + rl) * DIM + e0 + wc * 64 + c;
      float val = 0.f;
#pragma unroll
      for (int n = 0; n < 4; ++n)
        val += (acc[m][n][i] + wkrl[n]) * bf2f(xrow[n * 16]);
      val += __shfl_xor(val, 1); val += __shfl_xor(val, 2);
      val += __shfl_xor(val, 4); val += __shfl_xor(val, 8);
      if (c == 0) red[wc * 256 + rl] = val;
    }
  }
  __syncthreads();
  if (tid < 256) {
    const float s = red[tid] + red[256 + tid] + red[512 + tid] + red[768 + tid];
    rdpart[(size_t)ct * 65536 + j0 + tid] = s;
  }
}

// ---------- gemm2: rd/Rsum from rdpart; V = Xb @ Wvb^T; vs/vw reduced in-block;
//            out = (rd_j/R - 1/s)*V + ((1-rd_j/R)/s)*vs + (1/(sR))*vw ----------
__global__ __launch_bounds__(512, 2) void gemm2_f(const unsigned short* __restrict__ Xb,
                                                  const unsigned short* __restrict__ Wvb,
                                                  const float* __restrict__ rdpart,
                                                  float* __restrict__ out) {
  __shared__ unsigned short lds[65536];
  __shared__ float rdl[256];
  __shared__ float wsum[4];
  const int tid = threadIdx.x;
  const int lane = tid & 63, w = tid >> 6;
  const int wr = w >> 2, wc = w & 3;
  const int c = lane & 15, g = lane >> 4;
  const int grd = ((g ^ ((c >> 1) & 3))) * 8;

  const int work = (blockIdx.x & 7) * 64 + (blockIdx.x >> 3);
  const int rt = work >> 1, ct = work & 1;
  const int j0 = rt * 256, e0 = ct * 256;
  const int b = rt;  // 256-row tile == one batch

  // rd + Rsum (tiny, before any pipeline loads so __syncthreads drains nothing)
  if (tid < 256) {
    float v = (rdpart[(size_t)b * SLEN + tid] + rdpart[65536 + (size_t)b * SLEN + tid]) * SCALE;
    v = fminf(fmaxf(v, -5.0f), 7.0f);
    const float r = expf(v);
    rdl[tid] = r;
    float t = r;
    t += __shfl_xor(t, 1);  t += __shfl_xor(t, 2);  t += __shfl_xor(t, 4);
    t += __shfl_xor(t, 8);  t += __shfl_xor(t, 16); t += __shfl_xor(t, 32);
    if ((tid & 63) == 0) wsum[tid >> 6] = t;
  }
  __syncthreads();

  const int rA = tid >> 2;
  const int gl = (tid & 3) ^ ((rA >> 1) & 3);
  const unsigned short* sAp = Xb + (size_t)(j0 + rA) * DIM + gl * 8;
  const unsigned short* sBp = Wvb + (size_t)(e0 + rA) * DIM + gl * 8;
  unsigned short* lw = lds + (w << 9);

  GEMM_PROLOGUE()
  GEMM_MAIN_LOOP()

  // ---- in-block vs/vw reduction over the 256 rows (= full batch) ----
  float vsp[4] = {0.f, 0.f, 0.f, 0.f}, vwp[4] = {0.f, 0.f, 0.f, 0.f};
#pragma unroll
  for (int m = 0; m < 8; ++m) {
#pragma unroll
    for (int i = 0; i < 4; ++i) {
      const int rl = wr * 128 + m * 16 + 4 * g + i;
      const float rr = rdl[rl];
#pragma unroll
      for (int n = 0; n < 4; ++n) {
        vsp[n] += acc[m][n][i];
        vwp[n] += rr * acc[m][n][i];
      }
    }
  }
#pragma unroll
  for (int n = 0; n < 4; ++n) {
    vsp[n] += __shfl_xor(vsp[n], 16); vsp[n] += __shfl_xor(vsp[n], 32);
    vwp[n] += __shfl_xor(vwp[n], 16); vwp[n] += __shfl_xor(vwp[n], 32);
  }
  __syncthreads();  // pipeline LDS free now
  float* red = (float*)lds;  // [2][8 waves][4 n][16 c]
  if (g == 0) {
#pragma unroll
    for (int n = 0; n < 4; ++n) {
      red[(w * 4 + n) * 16 + c] = vsp[n];
      red[512 + (w * 4 + n) * 16 + c] = vwp[n];
    }
  }
  __syncthreads();
  const float Rb = wsum[0] + wsum[1] + wsum[2] + wsum[3];
  const float invR = 1.0f / Rb;
  const float gam = invR * 0.00390625f;
  const int wo = w ^ 4;  // other wr half, same wc
  float vsf[4], vwf[4];
#pragma unroll
  for (int n = 0; n < 4; ++n) {
    vsf[n] = red[(w * 4 + n) * 16 + c] + red[(wo * 4 + n) * 16 + c];
    vwf[n] = red[512 + (w * 4 + n) * 16 + c] + red[512 + (wo * 4 + n) * 16 + c];
  }
#pragma unroll
  for (int m = 0; m < 8; ++m) {
#pragma unroll
    for (int i = 0; i < 4; ++i) {
      const int rl = wr * 128 + m * 16 + 4 * g + i;
      const float tt = rdl[rl] * invR;
      const float al = tt - 0.00390625f;
      const float be = (1.0f - tt) * 0.00390625f;
      float* orow = out + (size_t)(j0 + rl) * DIM + e0 + wc * 64 + c;
#pragma unroll
      for (int n = 0; n < 4; ++n)
        orow[n * 16] = al * acc[m][n][i] + be * vsf[n] + gam * vwf[n];
    }
  }
}

// =================== fallback prep kernels (round-1 verified) ===================
__global__ __launch_bounds__(256) void prep_mt(const float* __restrict__ Wq,
                                               const float* __restrict__ Wk,
                                               unsigned short* __restrict__ Mt) {
  __shared__ float As[32][33];
  __shared__ float Bs[32][33];
  const int e0 = (blockIdx.x & 15) * 32;
  const int d0 = (blockIdx.x >> 4) * 32;
  const int tid = threadIdx.x;
  const int tm = (tid & 15) * 2;
  const int tn = (tid >> 4) * 2;
  const int lf = tid >> 3;
  const int lc = (tid & 7) * 4;
  float a00 = 0.f, a01 = 0.f, a10 = 0.f, a11 = 0.f;
  for (int f0 = 0; f0 < DIM; f0 += 32) {
    __syncthreads();
    const float4 a = *reinterpret_cast<const float4*>(Wk + (size_t)(f0 + lf) * DIM + e0 + lc);
    const float4 b = *reinterpret_cast<const float4*>(Wq + (size_t)(f0 + lf) * DIM + d0 + lc);
    As[lf][lc] = a.x; As[lf][lc + 1] = a.y; As[lf][lc + 2] = a.z; As[lf][lc + 3] = a.w;
    Bs[lf][lc] = b.x; Bs[lf][lc + 1] = b.y; Bs[lf][lc + 2] = b.z; Bs[lf][lc + 3] = b.w;
    __syncthreads();
#pragma unroll
    for (int k = 0; k < 32; ++k) {
      const float x0 = As[k][tm], x1 = As[k][tm + 1];
      const float y0 = Bs[k][tn], y1 = Bs[k][tn + 1];
      a00 += x0 * y0; a01 += x0 * y1; a10 += x1 * y0; a11 += x1 * y1;
    }
  }
  Mt[(size_t)(e0 + tm) * DIM + d0 + tn] = (unsigned short)f2bf(a00);
  Mt[(size_t)(e0 + tm) * DIM + d0 + tn + 1] = (unsigned short)f2bf(a01);
  Mt[(size_t)(e0 + tm + 1) * DIM + d0 + tn] = (unsigned short)f2bf(a10);
  Mt[(size_t)(e0 + tm + 1) * DIM + d0 + tn + 1] = (unsigned short)f2bf(a11);
}

__global__ __launch_bounds__(256) void conv_wv(const float* __restrict__ Wv,
                                               unsigned short* __restrict__ Wvb) {
  const int idx = (blockIdx.x * 256 + threadIdx.x) * 4;
  const float4 v = *reinterpret_cast<const float4*>(Wv + idx);
  uint2 p;
  p.x = f2bf(v.x) | (f2bf(v.y) << 16);
  p.y = f2bf(v.z) | (f2bf(v.w) << 16);
  *reinterpret_cast<uint2*>(Wvb + idx) = p;
}

__global__ __launch_bounds__(256) void wkr_k2(const float* __restrict__ Wk,
                                              const float* __restrict__ rq,
                                              float* __restrict__ wkr) {
  __shared__ float rqs[DIM];
  const int tid = threadIdx.x;
  rqs[tid] = rq[tid];
  rqs[tid + 256] = rq[tid + 256];
  __syncthreads();
  const int d = blockIdx.x * 256 + tid;
  float s = 0.f;
#pragma unroll 8
  for (int f = 0; f < DIM; ++f) s += Wk[(size_t)f * DIM + d] * rqs[f];
  wkr[d] = s;
}

// =================== round-1 fallback main kernels (verified) ===================
__global__ __launch_bounds__(256, 2) void pass1_fb(
    const float* __restrict__ X, const unsigned short* __restrict__ Mt,
    const float* __restrict__ wkr, float* __restrict__ rd_out,
    float* __restrict__ Rsum, float* __restrict__ xsum, float* __restrict__ xw) {
  __shared__ __align__(16) unsigned short Xs[TS * LDX];
  __shared__ __align__(16) unsigned short Bsh[64 * LDB];
  __shared__ float wkrs[DIM];
  __shared__ float dacc[TS];
  __shared__ float rds[TS];
  const int tid = threadIdx.x;
  const int b = blockIdx.x & 255;
  const int s0 = (blockIdx.x >> 8) * TS;
  const int lane = tid & 63;
  const int wave = tid >> 6;
  const int wr = wave >> 1, wc = wave & 1;
  const int g = lane >> 4, c = lane & 15;
#pragma unroll 4
  for (int r = 0; r < TS; ++r) {
    const float2 v = *reinterpret_cast<const float2*>(
        X + ((size_t)(s0 + r) * BATCH + b) * DIM + tid * 2);
    Xs[r * LDX + tid * 2] = (unsigned short)f2bf(v.x);
    Xs[r * LDX + tid * 2 + 1] = (unsigned short)f2bf(v.y);
  }
  wkrs[tid] = wkr[tid];
  wkrs[tid + 256] = wkr[tid + 256];
  if (tid < TS) dacc[tid] = 0.f;
  float dp0[4] = {0.f, 0.f, 0.f, 0.f};
  float dp1[4] = {0.f, 0.f, 0.f, 0.f};
  for (int et = 0; et < 8; ++et) {
    const int e0 = et * 64;
    f32x4 acc00 = {0.f,0.f,0.f,0.f}, acc01 = {0.f,0.f,0.f,0.f};
    f32x4 acc10 = {0.f,0.f,0.f,0.f}, acc11 = {0.f,0.f,0.f,0.f};
    for (int kc0 = 0; kc0 < DIM; kc0 += KC) {
      __syncthreads();
      {
        const int e = tid >> 2;
        const int kq = (tid & 3) * 16;
        const uint4* src = reinterpret_cast<const uint4*>(Mt + (size_t)(e0 + e) * DIM + kc0 + kq);
        const uint4 w0 = src[0];
        const uint4 w1 = src[1];
        *reinterpret_cast<uint4*>(&Bsh[e * LDB + kq]) = w0;
        *reinterpret_cast<uint4*>(&Bsh[e * LDB + kq + 8]) = w1;
      }
      __syncthreads();
#pragma unroll
      for (int ks = 0; ks < KC; ks += 32) {
        const int ka = kc0 + ks + 8 * g;
        const int kb = ks + 8 * g;
        const v8bf fa0 = ld8(&Xs[(32 * wr + c) * LDX + ka]);
        const v8bf fa1 = ld8(&Xs[(32 * wr + 16 + c) * LDX + ka]);
        const v8bf fb0 = ld8(&Bsh[(32 * wc + c) * LDB + kb]);
        const v8bf fb1 = ld8(&Bsh[(32 * wc + 16 + c) * LDB + kb]);
        acc00 = MFMA(fa0, fb0, acc00);
        acc01 = MFMA(fa0, fb1, acc01);
        acc10 = MFMA(fa1, fb0, acc10);
        acc11 = MFMA(fa1, fb1, acc11);
      }
    }
#pragma unroll
    for (int i = 0; i < 4; ++i) {
      const int r0 = 32 * wr + 4 * g + i;
      const int ec0 = e0 + 32 * wc + c;
      const float w0 = wkrs[ec0], w1 = wkrs[ec0 + 16];
      dp0[i] += (acc00[i] + w0) * bf2f(Xs[r0 * LDX + ec0]) +
                (acc01[i] + w1) * bf2f(Xs[r0 * LDX + ec0 + 16]);
      dp1[i] += (acc10[i] + w0) * bf2f(Xs[(r0 + 16) * LDX + ec0]) +
                (acc11[i] + w1) * bf2f(Xs[(r0 + 16) * LDX + ec0 + 16]);
    }
  }
#pragma unroll
  for (int i = 0; i < 4; ++i) {
    float v0 = dp0[i], v1 = dp1[i];
    v0 += __shfl_xor(v0, 1); v0 += __shfl_xor(v0, 2);
    v0 += __shfl_xor(v0, 4); v0 += __shfl_xor(v0, 8);
    v1 += __shfl_xor(v1, 1); v1 += __shfl_xor(v1, 2);
    v1 += __shfl_xor(v1, 4); v1 += __shfl_xor(v1, 8);
    if (c == 0) {
      atomicAdd(&dacc[32 * wr + 4 * g + i], v0);
      atomicAdd(&dacc[32 * wr + 16 + 4 * g + i], v1);
    }
  }
  __syncthreads();
  if (tid < TS) {
    float sc = dacc[tid] * SCALE;
    sc = fminf(fmaxf(sc, -5.0f), 7.0f);
    const float r = expf(sc);
    rds[tid] = r;
    rd_out[(size_t)b * SLEN + s0 + tid] = r;
    float t = r;
    t += __shfl_xor(t, 1); t += __shfl_xor(t, 2); t += __shfl_xor(t, 4);
    t += __shfl_xor(t, 8); t += __shfl_xor(t, 16); t += __shfl_xor(t, 32);
    if (tid == 0) atomicAdd(&Rsum[b], t);
  }
  __syncthreads();
#pragma unroll
  for (int dd = 0; dd < 2; ++dd) {
    const int d = tid + dd * 256;
    float s1 = 0.f, s2 = 0.f;
    for (int r = 0; r < TS; ++r) {
      const float xv = bf2f(Xs[r * LDX + d]);
      s1 += xv;
      s2 += rds[r] * xv;
    }
    atomicAdd(&xsum[(size_t)b * DIM + d], s1);
    atomicAdd(&xw[(size_t)b * DIM + d], s2);
  }
}

__global__ __launch_bounds__(256, 2) void pass2_fb(
    const float* __restrict__ X, const unsigned short* __restrict__ Wvb,
    const float* __restrict__ rd, const float* __restrict__ Rsum,
    const float* __restrict__ xsum, const float* __restrict__ xw,
    float* __restrict__ out) {
  __shared__ __align__(16) unsigned short Zs[TS * LDX];
  __shared__ __align__(16) unsigned short Bsh[64 * LDB];
  __shared__ float xss[DIM];
  __shared__ float xws[DIM];
  __shared__ float rds[TS];
  const int tid = threadIdx.x;
  const int b = blockIdx.x & 255;
  const int s0 = (blockIdx.x >> 8) * TS;
  const int lane = tid & 63;
  const int wave = tid >> 6;
  const int wr = wave >> 1, wc = wave & 1;
  const int g = lane >> 4, c = lane & 15;
  xss[tid] = xsum[(size_t)b * DIM + tid];
  xss[tid + 256] = xsum[(size_t)b * DIM + tid + 256];
  xws[tid] = xw[(size_t)b * DIM + tid];
  xws[tid + 256] = xw[(size_t)b * DIM + tid + 256];
  if (tid < TS) rds[tid] = rd[(size_t)b * SLEN + s0 + tid];
  const float Rb = Rsum[b];
  const float invR = 1.0f / Rb;
  const float gam = invR * (1.0f / 256.0f);
  __syncthreads();
#pragma unroll 4
  for (int r = 0; r < TS; ++r) {
    const float rv = rds[r];
    const float al = rv * invR - (1.0f / 256.0f);
    const float be = (1.0f - rv * invR) * (1.0f / 256.0f);
    const float2 v = *reinterpret_cast<const float2*>(
        X + ((size_t)(s0 + r) * BATCH + b) * DIM + tid * 2);
    const int d0 = tid * 2;
    Zs[r * LDX + d0] = (unsigned short)f2bf(al * v.x + be * xss[d0] + gam * xws[d0]);
    Zs[r * LDX + d0 + 1] = (unsigned short)f2bf(al * v.y + be * xss[d0 + 1] + gam * xws[d0 + 1]);
  }
  const size_t outbase = ((size_t)b * SLEN + s0) * DIM;
  for (int et = 0; et < 8; ++et) {
    const int e0 = et * 64;
    f32x4 acc00 = {0.f,0.f,0.f,0.f}, acc01 = {0.f,0.f,0.f,0.f};
    f32x4 acc10 = {0.f,0.f,0.f,0.f}, acc11 = {0.f,0.f,0.f,0.f};
    for (int kc0 = 0; kc0 < DIM; kc0 += KC) {
      __syncthreads();
      {
        const int e = tid >> 2;
        const int kq = (tid & 3) * 16;
        const uint4* src = reinterpret_cast<const uint4*>(Wvb + (size_t)(e0 + e) * DIM + kc0 + kq);
        const uint4 w0 = src[0];
        const uint4 w1 = src[1];
        *reinterpret_cast<uint4*>(&Bsh[e * LDB + kq]) = w0;
        *reinterpret_cast<uint4*>(&Bsh[e * LDB + kq + 8]) = w1;
      }
      __syncthreads();
#pragma unroll
      for (int ks = 0; ks < KC; ks += 32) {
        const int ka = kc0 + ks + 8 * g;
        const int kb = ks + 8 * g;
        const v8bf fa0 = ld8(&Zs[(32 * wr + c) * LDX + ka]);
        const v8bf fa1 = ld8(&Zs[(32 * wr + 16 + c) * LDX + ka]);
        const v8bf fb0 = ld8(&Bsh[(32 * wc + c) * LDB + kb]);
        const v8bf fb1 = ld8(&Bsh[(32 * wc + 16 + c) * LDB + kb]);
        acc00 = MFMA(fa0, fb0, acc00);
        acc01 = MFMA(fa0, fb1, acc01);
        acc10 = MFMA(fa1, fb0, acc10);
        acc11 = MFMA(fa1, fb1, acc11);
      }
    }
#pragma unroll
    for (int i = 0; i < 4; ++i) {
      const int r0 = 32 * wr + 4 * g + i;
      const int c0 = e0 + 32 * wc + c;
      out[outbase + (size_t)r0 * DIM + c0] = acc00[i];
      out[outbase + (size_t)r0 * DIM + c0 + 16] = acc01[i];
      out[outbase + (size_t)(r0 + 16) * DIM + c0] = acc10[i];
      out[outbase + (size_t)(r0 + 16) * DIM + c0 + 16] = acc11[i];
    }
  }
}

extern "C" void kernel_launch(void* const* d_in, const int* in_sizes, int n_in,
                              void* d_out, int out_size, void* d_ws, size_t ws_size,
                              hipStream_t stream) {
  (void)in_sizes; (void)n_in; (void)out_size;
  const float* X = (const float*)d_in[0];
  const float* Wq = (const float*)d_in[1];
  const float* Wk = (const float*)d_in[2];
  const float* Wv = (const float*)d_in[3];
  const float* rq = (const float*)d_in[4];
  float* out = (float*)d_out;
  char* ws = (char*)d_ws;

  unsigned short* Mt = (unsigned short*)(ws + 0);        // 512 KB
  unsigned short* Wvb = (unsigned short*)(ws + 524288);  // 512 KB

  const size_t NEED = 69206016;  // 2 MB headers + 64 MB Xb
  if (ws_size >= NEED) {
    float* wkr = (float*)(ws + 1048576);            // 2 KB  (plain stores)
    float* rdpart = (float*)(ws + 1052672);         // 512 KB [2][65536] (plain stores)
    unsigned short* Xb = (unsigned short*)(ws + 2097152);  // 64 MB

    prep_all<<<dim3(2562), dim3(256), 0, stream>>>(X, Wq, Wk, Wv, rq, Xb, Mt, Wvb, wkr);
    gemm1_dp<<<dim3(512), dim3(512), 0, stream>>>(Xb, Mt, wkr, rdpart);
    gemm2_f<<<dim3(512), dim3(512), 0, stream>>>(Xb, Wvb, rdpart, out);
  } else {
    // round-1 verified fallback (needs ~2.4 MB)
    float* rd = (float*)(ws + 1048576);
    float* wkr = (float*)(ws + 1310720);
    float* Rsum = (float*)(ws + 1312768);
    float* xsum = (float*)(ws + 1313792);
    float* xw = (float*)(ws + 1838080);
    zf<<<dim3(257), dim3(256), 0, stream>>>((float4*)(ws + 1310720), 65728);
    prep_mt<<<dim3(256), dim3(256), 0, stream>>>(Wq, Wk, Mt);
    conv_wv<<<dim3(256), dim3(256), 0, stream>>>(Wv, Wvb);
    wkr_k2<<<dim3(2), dim3(256), 0, stream>>>(Wk, rq, wkr);
    pass1_fb<<<dim3(1024), dim3(256), 0, stream>>>(X, Mt, wkr, rd, Rsum, xsum, xw);
    pass2_fb<<<dim3(1024), dim3(256), 0, stream>>>(X, Wvb, rd, Rsum, xsum, xw, out);
  }
}